// Round 1
// 535.113 us; speedup vs baseline: 1.1788x; 1.1788x over previous
//
#include <hip/hip_runtime.h>
#include <hip/hip_fp16.h>

constexpr int kNodes = 50000;
constexpr int kNE    = 800000;            // edges before self loops
constexpr int kFin   = 256;
constexpr int kC     = 32;
constexpr int kH     = 4;
constexpr int kHC    = 128;               // kH * kC
constexpr int kTN    = 16;                // nodes per k_embed block
constexpr int kWP    = 258;               // padded sWt row (2-way LDS alias = free)
constexpr float kEps   = 1e-5f;
constexpr float kSlope = 0.2f;
constexpr float kL2E   = 1.44269504f;     // log2(e): fold into att so exp is 1 instr
constexpr float kShift2 = 8.0f * 1.44269504f; // softmax-invariant shift (exp2 domain)

// ---- zero-fill
__global__ void __launch_bounds__(256) k_fill0(unsigned* __restrict__ p, int n) {
    int i = blockIdx.x * 256 + threadIdx.x;
    if (i < n) p[i] = 0u;
}

// ---- K1: h0 = relu(node_ln(x @ W_emb + b_emb)); jk = h0.
// 16 nodes/block; x staged (16KB), W staged TRANSPOSED pad-258 (33KB).
// Thread t = (c, n2): computes nodes n2 and n2+8. Inner: float4 x-broadcast +
// 2x float2 W-row reads per 4k. LN via 32-lane shfl.
__global__ void __launch_bounds__(256) k_embed(
    const float* __restrict__ x, const float* __restrict__ W, const float* __restrict__ b,
    const float* __restrict__ lnw, const float* __restrict__ lnb,
    float* __restrict__ h, float* __restrict__ jk) {
    __shared__ float sx[kTN * kFin];      // 16 KB
    __shared__ float sWt[kC * kWP];       // 33 KB
    int t = threadIdx.x;
    int n0 = blockIdx.x * kTN;            // 50000 = 3125 * 16 exact
    for (int i = t; i < kFin * kC; i += 256) {
        int k = i >> 5, c = i & 31;
        sWt[c * kWP + k] = W[i];
    }
    const float* xg = x + (long)n0 * kFin;
    for (int i = t; i < kTN * kFin; i += 256) sx[i] = xg[i];
    __syncthreads();
    int c = t & 31, n2 = t >> 5;          // n2 = 0..7
    const float* xa = sx + n2 * kFin;
    const float* xb = sx + (n2 + 8) * kFin;
    const float* wrow = sWt + c * kWP;
    float acc0 = 0.f, acc1 = 0.f;
    #pragma unroll 8
    for (int k = 0; k < kFin; k += 4) {
        float4 x0 = *(const float4*)(xa + k);
        float4 x1 = *(const float4*)(xb + k);
        float2 w0 = *(const float2*)(wrow + k);
        float2 w1 = *(const float2*)(wrow + k + 2);
        acc0 += x0.x * w0.x + x0.y * w0.y + x0.z * w1.x + x0.w * w1.y;
        acc1 += x1.x * w0.x + x1.y * w0.y + x1.z * w1.x + x1.w * w1.y;
    }
    float bc = b[c], lw = lnw[c], lb = lnb[c];
    // node n2
    {
        float y = acc0 + bc;
        float m = y;
        #pragma unroll
        for (int o = 1; o < 32; o <<= 1) m += __shfl_xor(m, o);
        m *= (1.f / kC);
        float xc = y - m, v = xc * xc;
        #pragma unroll
        for (int o = 1; o < 32; o <<= 1) v += __shfl_xor(v, o);
        v *= (1.f / kC);
        float out = fmaxf(xc * rsqrtf(v + kEps) * lw + lb, 0.f);
        int node = n0 + n2;
        h[node * kC + c] = out;
        jk[node * kC + c] = out;
    }
    // node n2 + 8
    {
        float y = acc1 + bc;
        float m = y;
        #pragma unroll
        for (int o = 1; o < 32; o <<= 1) m += __shfl_xor(m, o);
        m *= (1.f / kC);
        float xc = y - m, v = xc * xc;
        #pragma unroll
        for (int o = 1; o < 32; o <<= 1) v += __shfl_xor(v, o);
        v *= (1.f / kC);
        float out = fmaxf(xc * rsqrtf(v + kEps) * lw + lb, 0.f);
        int node = n0 + n2 + 8;
        h[node * kC + c] = out;
        jk[node * kC + c] = out;
    }
}

// ---- K2: xl = h@Wl + bl (fp16) ; xr = h@Wr + br (fp32).
// 256 threads: feature j x node-half; W columns in registers.
__global__ void __launch_bounds__(256) k_trans(
    const float* __restrict__ h,
    const float* __restrict__ Wl, const float* __restrict__ bl,
    const float* __restrict__ Wr, const float* __restrict__ br,
    __half* __restrict__ xl, float* __restrict__ xr) {
    __shared__ float s_h[32 * kC];
    int t = threadIdx.x;
    int j = t & 127, hf = t >> 7;
    float wl[kC], wr[kC];
    #pragma unroll
    for (int k = 0; k < kC; ++k) { wl[k] = Wl[k * kHC + j]; wr[k] = Wr[k * kHC + j]; }
    float blj = bl[j], brj = br[j];
    int n0 = blockIdx.x * 32;
    int nn = min(32, kNodes - n0);
    for (int i = t; i < nn * kC; i += 256) s_h[i] = h[n0 * kC + i];
    __syncthreads();
    int nend = min(nn, hf * 16 + 16);
    for (int n = hf * 16; n < nend; ++n) {
        const float4* h4 = (const float4*)(s_h + n * kC);
        float al = blj, ar = brj;
        #pragma unroll
        for (int kq = 0; kq < 8; ++kq) {
            float4 hv = h4[kq];
            al += hv.x * wl[kq*4] + hv.y * wl[kq*4+1] + hv.z * wl[kq*4+2] + hv.w * wl[kq*4+3];
            ar += hv.x * wr[kq*4] + hv.y * wr[kq*4+1] + hv.z * wr[kq*4+2] + hv.w * wr[kq*4+3];
        }
        long g = (long)(n0 + n) * kHC + j;
        xl[g] = __float2half(al);
        xr[g] = ar;
    }
}

// ---- CSR build (dst is layer-invariant: built ONCE)
__global__ void __launch_bounds__(256) k_hist(const int* __restrict__ dst, int* __restrict__ deg) {
    int e = blockIdx.x * 256 + threadIdx.x;
    if (e < kNE) atomicAdd(&deg[dst[e]], 1);
}

__global__ void __launch_bounds__(256) k_scan1(const int* __restrict__ deg,
                                               int* __restrict__ excl, int* __restrict__ bsum) {
    __shared__ int s[256];
    int t = threadIdx.x;
    int i = blockIdx.x * 256 + t;
    int v = (i < kNodes) ? deg[i] : 0;
    s[t] = v;
    __syncthreads();
    for (int o = 1; o < 256; o <<= 1) {
        int tv = (t >= o) ? s[t - o] : 0;
        __syncthreads();
        s[t] += tv;
        __syncthreads();
    }
    if (i < kNodes) excl[i] = s[t] - v;
    if (t == 255) bsum[blockIdx.x] = s[255];
}

__global__ void __launch_bounds__(256) k_scan2(int* __restrict__ bsum, int nb) {
    __shared__ int s[256];
    int t = threadIdx.x;
    int v = (t < nb) ? bsum[t] : 0;
    s[t] = v;
    __syncthreads();
    for (int o = 1; o < 256; o <<= 1) {
        int tv = (t >= o) ? s[t - o] : 0;
        __syncthreads();
        s[t] += tv;
        __syncthreads();
    }
    if (t < nb) bsum[t] = s[t];
}

__global__ void __launch_bounds__(256) k_scan3(int* __restrict__ excl, const int* __restrict__ bsum) {
    int i = blockIdx.x * 256 + threadIdx.x;
    if (i >= kNodes) return;
    if (blockIdx.x > 0) excl[i] += bsum[blockIdx.x - 1];
}

__global__ void __launch_bounds__(256) k_reorder(
    const int* __restrict__ src, const int* __restrict__ dst, const float* __restrict__ ea,
    const int* __restrict__ rowptr, int* __restrict__ cur,
    int* __restrict__ esrc, float* __restrict__ eea) {
    int e = blockIdx.x * 256 + threadIdx.x;
    if (e >= kNE) return;
    int d = dst[e];
    int pos = rowptr[d] + atomicAdd(&cur[d], 1);
    esrc[pos] = src[e];
    eea[pos]  = ea[e];
}

// ---- K3: fused edge phase, 2 features/lane, 1 wave/node, 4 nodes/block.
// Lane t owns features (2t, 2t+1); head = t>>4 (16 lanes/head).
// Edge metadata lives in registers: lanes 0-31 hold src (int bits), lanes
// 32-63 hold ea; broadcast per edge via __shfl. No LDS, no __syncthreads.
__global__ void __launch_bounds__(256) k_edge(
    const int* __restrict__ rowptr, const int* __restrict__ deg,
    const int* __restrict__ esrc, const float* __restrict__ eea,
    const __half* __restrict__ xl, float* __restrict__ xrg,
    const float* __restrict__ We, const float* __restrict__ att,
    const float* __restrict__ gat_b, float* __restrict__ ps, float* __restrict__ pq) {
    int t = threadIdx.x & 63;             // lane
    int w = threadIdx.x >> 6;             // wave 0..3
    int d = blockIdx.x * 4 + w;           // node (50000 = 12500 * 4 exact)
    const __half2* xl2 = (const __half2*)xl;
    long rowb = (long)d * 64;             // row offset in half2/float2 units

    float2 xrv = ((const float2*)xrg)[rowb + t];
    float2 Wev = ((const float2*)We)[t];
    float2 av  = ((const float2*)att)[t];
    av.x *= kL2E; av.y *= kL2E;           // fold ln2 into att -> single v_exp

    float2 xself = __half22float2(xl2[rowb + t]);

    // self loop (ea = 0)
    float z0 = xself.x + xrv.x, z1 = xself.y + xrv.y;
    z0 = fmaxf(z0, kSlope * z0); z1 = fmaxf(z1, kSlope * z1);
    float p = z0 * av.x + z1 * av.y;
    #pragma unroll
    for (int mm = 1; mm < 16; mm <<= 1) p += __shfl_xor(p, mm);
    float ee = __builtin_amdgcn_exp2f(p - kShift2);
    float l = ee, o0 = ee * xself.x, o1 = ee * xself.y;

    int base = rowptr[d], cnt = deg[d];
    for (int eoff = 0; eoff < cnt; eoff += 32) {
        int cc = min(32, cnt - eoff);
        float meta = 0.f;
        if (t < 32) {
            if (t < cc) meta = __int_as_float(esrc[base + eoff + t]);
        } else {
            int u = t - 32;
            if (u < cc) meta = eea[base + eoff + u];
        }
        int e = 0;
        for (; e + 8 <= cc; e += 8) {
            float2 xv[8]; float pv[8];
            #pragma unroll
            for (int u = 0; u < 8; ++u) {
                int s = __float_as_int(__shfl(meta, e + u));
                xv[u] = __half22float2(xl2[(long)s * 64 + t]);
            }
            #pragma unroll
            for (int u = 0; u < 8; ++u) {
                float eav = __shfl(meta, 32 + e + u);
                float zz0 = fmaf(eav, Wev.x, xrv.x) + xv[u].x;
                float zz1 = fmaf(eav, Wev.y, xrv.y) + xv[u].y;
                zz0 = fmaxf(zz0, kSlope * zz0);
                zz1 = fmaxf(zz1, kSlope * zz1);
                pv[u] = zz0 * av.x + zz1 * av.y;
            }
            #pragma unroll
            for (int mm = 1; mm < 16; mm <<= 1) {
                #pragma unroll
                for (int u = 0; u < 8; ++u) pv[u] += __shfl_xor(pv[u], mm);
            }
            #pragma unroll
            for (int u = 0; u < 8; ++u) {
                float eeu = __builtin_amdgcn_exp2f(pv[u] - kShift2);
                l += eeu;
                o0 = fmaf(eeu, xv[u].x, o0);
                o1 = fmaf(eeu, xv[u].y, o1);
            }
        }
        for (; e < cc; ++e) {
            int s = __float_as_int(__shfl(meta, e));
            float eav = __shfl(meta, 32 + e);
            float2 xv = __half22float2(xl2[(long)s * 64 + t]);
            float zz0 = fmaf(eav, Wev.x, xrv.x) + xv.x;
            float zz1 = fmaf(eav, Wev.y, xrv.y) + xv.y;
            zz0 = fmaxf(zz0, kSlope * zz0);
            zz1 = fmaxf(zz1, kSlope * zz1);
            float pe = zz0 * av.x + zz1 * av.y;
            #pragma unroll
            for (int mm = 1; mm < 16; mm <<= 1) pe += __shfl_xor(pe, mm);
            float eeu = __builtin_amdgcn_exp2f(pe - kShift2);
            l += eeu;
            o0 = fmaf(eeu, xv.x, o0);
            o1 = fmaf(eeu, xv.y, o1);
        }
    }
    float rl = __builtin_amdgcn_rcpf(l);
    float v0 = o0 * rl, v1 = o1 * rl;
    ((float2*)xrg)[rowb + t] = make_float2(v0, v1);   // g overwrites xr (row-private)
    float2 gb = ((const float2*)gat_b)[t];
    float vb0 = v0 + gb.x, vb1 = v1 + gb.y;
    float s = vb0 + vb1, q = vb0 * vb0 + vb1 * vb1;
    #pragma unroll
    for (int mm = 1; mm < 64; mm <<= 1) { s += __shfl_xor(s, mm); q += __shfl_xor(q, mm); }
    if (t == 0) { ps[d] = s; pq[d] = q; }
}

// ---- K4: reduce per-node partials -> stats[2].
__global__ void __launch_bounds__(1024) k_statsr(
    const float* __restrict__ ps, const float* __restrict__ pq, float* __restrict__ stats) {
    __shared__ float rs[1024], rq[1024];
    int t = threadIdx.x;
    float s = 0.f, q = 0.f;
    for (int i = t; i < kNodes; i += 1024) { s += ps[i]; q += pq[i]; }
    rs[t] = s; rq[t] = q;
    __syncthreads();
    for (int o = 512; o > 0; o >>= 1) {
        if (t < o) { rs[t] += rs[t + o]; rq[t] += rq[t + o]; }
        __syncthreads();
    }
    if (t == 0) { stats[0] = rs[0]; stats[1] = rq[0]; }
}

// ---- K5: h = relu(node_ln(relu(graph_ln(g+gat_b)) @ lin_w + lin_b)); jk_out = max(jk_in, h)
__global__ void __launch_bounds__(256) k_post(
    const float* __restrict__ g, const float* __restrict__ gat_b,
    const float* __restrict__ ln1w, const float* __restrict__ ln1b,
    const float* __restrict__ linw, const float* __restrict__ linb,
    const float* __restrict__ ln2w, const float* __restrict__ ln2b,
    const float* __restrict__ stats, const float* __restrict__ jk_in,
    float* __restrict__ h, float* __restrict__ jk_out) {
    __shared__ float s_lw[kHC * kC];      // 16 KB
    __shared__ float s_vb[8 * kHC];       // 4 KB
    int t = threadIdx.x;
    int n0 = blockIdx.x * 8;
    const float inv = 1.f / ((float)kNodes * kHC);
    float mean = stats[0] * inv;
    float var  = stats[1] * inv - mean * mean;
    float rstd = rsqrtf(var + kEps);
    for (int i = t; i < kHC * kC; i += 256) s_lw[i] = linw[i];
    for (int i = t; i < 8 * kHC; i += 256) {
        int node = n0 + (i >> 7), f = i & 127;
        float a = (g[(long)node * kHC + f] + gat_b[f] - mean) * rstd * ln1w[f] + ln1b[f];
        s_vb[i] = fmaxf(a, 0.f);
    }
    __syncthreads();
    int n = t >> 5, c = t & 31;
    int node = n0 + n;
    float acc = linb[c];
    #pragma unroll 8
    for (int k = 0; k < kHC; ++k) acc += s_vb[n * kHC + k] * s_lw[k * kC + c];
    float m = acc;
    #pragma unroll
    for (int mm = 1; mm < 32; mm <<= 1) m += __shfl_xor(m, mm);
    m *= (1.f / kC);
    float dd = acc - m;
    float q = dd * dd;
    #pragma unroll
    for (int mm = 1; mm < 32; mm <<= 1) q += __shfl_xor(q, mm);
    q *= (1.f / kC);
    float out = dd * rsqrtf(q + kEps) * ln2w[c] + ln2b[c];
    out = fmaxf(out, 0.f);
    h[node * kC + c] = out;
    jk_out[node * kC + c] = fmaxf(jk_in[node * kC + c], out);
}

extern "C" void kernel_launch(void* const* d_in, const int* in_sizes, int n_in,
                              void* d_out, int out_size, void* d_ws, size_t ws_size,
                              hipStream_t stream) {
    (void)in_sizes; (void)n_in; (void)out_size; (void)ws_size;
    const float* x     = (const float*)d_in[0];
    const int*   ei    = (const int*)d_in[1];
    const int*   src   = ei;
    const int*   dst   = ei + kNE;
    const float* ea    = (const float*)d_in[2];
    const float* W_emb = (const float*)d_in[3];
    const float* b_emb = (const float*)d_in[4];
    const float* ln0w  = (const float*)d_in[5];
    const float* ln0b  = (const float*)d_in[6];
    const float* Wl    = (const float*)d_in[7];
    const float* bl    = (const float*)d_in[8];
    const float* Wr    = (const float*)d_in[9];
    const float* br    = (const float*)d_in[10];
    const float* We    = (const float*)d_in[11];
    const float* att   = (const float*)d_in[12];
    const float* gat_b = (const float*)d_in[13];
    const float* ln1w  = (const float*)d_in[14];
    const float* ln1b  = (const float*)d_in[15];
    const float* linw  = (const float*)d_in[16];
    const float* linb  = (const float*)d_in[17];
    const float* ln2w  = (const float*)d_in[18];
    const float* ln2b  = (const float*)d_in[19];

    char* wsb = (char*)d_ws;
    float*  h      = (float*)(wsb);                 // 6.4e6 B
    float*  jk     = (float*)(wsb +  6400000);      // 6.4e6 B
    float*  xrg    = (float*)(wsb + 12800000);      // 25.6e6 B (xr, later g)
    __half* xl     = (__half*)(wsb + 38400000);     // 12.8e6 B
    int*    esrc   = (int*)(wsb + 51200000);        // 3.2e6 B
    float*  eea    = (float*)(wsb + 54400000);      // 3.2e6 B
    int*    deg    = (int*)(wsb + 57600000);        // 0.2e6 B
    int*    cur    = (int*)(wsb + 57800000);        // 0.2e6 B
    int*    rowptr = (int*)(wsb + 58000000);        // 0.2e6 B
    int*    bsum   = (int*)(wsb + 58200000);        // 1 KB
    float*  stats  = (float*)(wsb + 58201024);      // 8 B
    float*  ps     = (float*)(wsb + 58300000);      // 0.2e6 B
    float*  pq     = (float*)(wsb + 58500000);      // 0.2e6 B

    const int scanBlocks  = (kNodes + 255) / 256;        // 196
    const int embedBlocks = kNodes / kTN;                // 3125 exact
    const int transBlocks = (kNodes + 31) / 32;          // 1563
    const int eBlocks     = (kNE + 255) / 256;
    const int edgeBlocks  = kNodes / 4;                  // 12500 exact, 4 nodes/block
    const int postBlocks  = kNodes / 8;                  // 6250 exact

    hipLaunchKernelGGL(k_embed, dim3(embedBlocks), dim3(256), 0, stream,
                       x, W_emb, b_emb, ln0w, ln0b, h, jk);
    // CSR build (once; dst is layer-invariant)
    hipLaunchKernelGGL(k_fill0, dim3((2 * kNodes + 255) / 256), dim3(256), 0, stream,
                       (unsigned*)deg, 2 * kNodes);      // deg + cur
    hipLaunchKernelGGL(k_hist, dim3(eBlocks), dim3(256), 0, stream, dst, deg);
    hipLaunchKernelGGL(k_scan1, dim3(scanBlocks), dim3(256), 0, stream, deg, rowptr, bsum);
    hipLaunchKernelGGL(k_scan2, dim3(1), dim3(256), 0, stream, bsum, scanBlocks);
    hipLaunchKernelGGL(k_scan3, dim3(scanBlocks), dim3(256), 0, stream, rowptr, bsum);
    hipLaunchKernelGGL(k_reorder, dim3(eBlocks), dim3(256), 0, stream,
                       src, dst, ea, rowptr, cur, esrc, eea);
    for (int l = 0; l < 2; ++l) {
        hipLaunchKernelGGL(k_trans, dim3(transBlocks), dim3(256), 0, stream,
                           h, Wl + l * kC * kHC, bl + l * kHC,
                           Wr + l * kC * kHC, br + l * kHC, xl, xrg);
        hipLaunchKernelGGL(k_edge, dim3(edgeBlocks), dim3(256), 0, stream,
                           rowptr, deg, esrc, eea, xl, xrg,
                           We + l * kHC, att + l * kH * kC, gat_b + l * kHC, ps, pq);
        hipLaunchKernelGGL(k_statsr, dim3(1), dim3(1024), 0, stream, ps, pq, stats);
        hipLaunchKernelGGL(k_post, dim3(postBlocks), dim3(256), 0, stream,
                           xrg, gat_b + l * kHC, ln1w + l * kHC, ln1b + l * kHC,
                           linw + l * kHC * kC, linb + l * kC,
                           ln2w + l * kC, ln2b + l * kC, stats, jk,
                           h, (l == 1) ? (float*)d_out : jk);
    }
}